// Round 9
// baseline (308.418 us; speedup 1.0000x reference)
//
#include <hip/hip_runtime.h>

#define NT   49      // tokens per window
#define HD   32      // head dim
#define NH   4
#define DIM  128
#define SCALEQ 0.17677669529663687f  // 32^-0.5

typedef __attribute__((ext_vector_type(8))) short short8;
typedef __attribute__((ext_vector_type(4))) short short4v;
typedef __attribute__((ext_vector_type(4))) float floatx4;
// may_alias versions: all LDS/global type-punned accesses go through these so
// TBAA cannot reorder stores/loads across the barrier-free phase chain.
typedef short8 short8a __attribute__((may_alias));
typedef short4v short4a __attribute__((may_alias));
typedef unsigned long long ulla __attribute__((may_alias));
typedef unsigned long long ull;

// R9: conversions are the hand-rolled RNE fp32->bf16 that passed R0-R5
// bit-exact. Both cvt experiments are quarantined: <hip/hip_bf16.h> (R6/R7:
// container died twice) and inline-asm v_cvt_pk_bf16_f32 (R8: NaN output —
// packed-op semantics on gfx950 differ from assumption; garbage high half
// -> exp overflow -> inf*0 NaN). Do not reintroduce without an isolated A/B.
__device__ __forceinline__ short f2b(float f) {
    union { float f; unsigned u; } v; v.f = f;
    return (short)((v.u + 0x7fffu + ((v.u >> 16) & 1u)) >> 16);  // RNE fp32->bf16
}
__device__ __forceinline__ ull pk4(float a, float b, float c, float d) {
    return  (ull)(unsigned short)f2b(a)
         | ((ull)(unsigned short)f2b(b) << 16)
         | ((ull)(unsigned short)f2b(c) << 32)
         | ((ull)(unsigned short)f2b(d) << 48);
}
__device__ __forceinline__ short4v pack4(floatx4 a) {
    short4v r;
    r[0] = f2b(a[0]); r[1] = f2b(a[1]); r[2] = f2b(a[2]); r[3] = f2b(a[3]);
    return r;
}
__device__ __forceinline__ float b2f(short s) {
    union { unsigned u; float f; } v; v.u = ((unsigned)(unsigned short)s) << 16;
    return v.f;
}

// K=16 MFMA (A[row=cc][k=qq*4+e], B[col=cc][k=qq*4+e]) — HW-validated in
// R3/R4/R5. Fallback: zero-padded K=32 (elements at e=0..3 map to k32=qq*8+e
// identically for A and B, so the contraction equals the K=16 product).
#if __has_builtin(__builtin_amdgcn_mfma_f32_16x16x16bf16_1k)
__device__ __forceinline__ floatx4 MFMA16(short4v a, short4v b, floatx4 c) {
    return __builtin_amdgcn_mfma_f32_16x16x16bf16_1k(a, b, c, 0, 0, 0);
}
#else
__device__ __forceinline__ floatx4 MFMA16(short4v a, short4v b, floatx4 c) {
    short8 a8 = {a[0], a[1], a[2], a[3], 0, 0, 0, 0};
    short8 b8 = {b[0], b[1], b[2], b[3], 0, 0, 0, 0};
    return __builtin_amdgcn_mfma_f32_16x16x32_bf16(a8, b8, c, 0, 0, 0);
}
#endif

// ---------- prologue ----------
// 64 blocks (one per window). Stage ridx/btab/mask in LDS, emit the combined
// bias+mask table (cmb) in MFMA frag layout + convert weights to bf16.
// cmb[wdw][h][(it*4+jt)*256 + qq*64 + cc*4 + r] bf16 = bias[h] + mask[wdw];
// col>=49 -> -1e30 (masks key pads via C-init), row>=49 -> 0. wqkv Q-section
// pre-scaled by hd^-0.5.
__global__ __launch_bounds__(256) void wmsa_prep(
        const float* __restrict__ qkvw, const float* __restrict__ projw,
        const float* __restrict__ btab, const int* __restrict__ ridx,
        const float* __restrict__ mask,
        short* __restrict__ wqkv, short* __restrict__ wproj,
        short* __restrict__ cmb) {
    __shared__ __align__(16) int   s_ridx[NT * NT];        // 9604 B
    __shared__ __align__(16) float s_btab[169 * 4];        // 2704 B (float4 rows)
    __shared__ __align__(16) float s_mask[NT * NT];        // 9604 B

    const int wdw = blockIdx.x;
    const int tid = threadIdx.x;

    // ---- weight conversion: one float4 group per thread (grid covers all) ----
    {
        int g = wdw * 256 + tid;          // 0..16383; 3*128*128/4 = 12288 qkv groups
        const float* src = (g < 12288) ? (qkvw + g * 4) : (projw + (g - 12288) * 4);
        float4 v = *(const float4*)src;
        float s = (g < 4096) ? SCALEQ : 1.0f;   // first DIM*DIM elements = Q rows
        ull pk = pk4(v.x * s, v.y * s, v.z * s, v.w * s);
        if (g < 12288) *(ulla*)(wqkv + g * 4) = pk;
        else           *(ulla*)(wproj + (g - 12288) * 4) = pk;
    }

    // ---- stage gather tables (coalesced) ----
    for (int i = tid; i < NT * NT; i += 256) s_ridx[i] = ridx[i];
    for (int i = tid; i < 169 * 4; i += 256) s_btab[i] = btab[i];
    {
        const float* mw = mask + (size_t)wdw * NT * NT;
        for (int i = tid; i < NT * NT; i += 256) s_mask[i] = mw[i];
    }
    __syncthreads();

    // ---- emit combined table for this window: 4 heads x 4096 bf16 ----
    // group g encodes (it,jt,qq,cc); the 4 consecutive shorts are r=0..3.
    #pragma unroll
    for (int gi = 0; gi < 4; ++gi) {
        int g = gi * 256 + tid;                       // 0..1023
        int cc = g & 15, qq = (g >> 4) & 3, tile = g >> 6;
        int it = tile >> 2, jt = tile & 3;
        int col = jt * 16 + cc;
        int rowb = it * 16 + qq * 4;
        if (col >= NT) {
            ull m16 = (unsigned short)f2b(-1e30f);
            ull pk = m16 | (m16 << 16) | (m16 << 32) | (m16 << 48);
            #pragma unroll
            for (int h = 0; h < NH; ++h)
                *(ulla*)(cmb + (((size_t)wdw * NH + h) << 12) + g * 4) = pk;
        } else {
            float bt[4][4], mv[4];
            #pragma unroll
            for (int r = 0; r < 4; ++r) {
                int row = rowb + r;
                if (row >= NT) {
                    bt[r][0] = bt[r][1] = bt[r][2] = bt[r][3] = 0.f;
                    mv[r] = 0.f;
                } else {
                    int ri = s_ridx[row * NT + col];
                    float4 b4 = *(const float4*)(s_btab + ri * 4);  // all 4 heads
                    bt[r][0] = b4.x; bt[r][1] = b4.y; bt[r][2] = b4.z; bt[r][3] = b4.w;
                    mv[r] = s_mask[row * NT + col];
                }
            }
            #pragma unroll
            for (int h = 0; h < NH; ++h) {
                ull pk = pk4(bt[0][h] + mv[0], bt[1][h] + mv[1],
                             bt[2][h] + mv[2], bt[3][h] + mv[3]);
                *(ulla*)(cmb + (((size_t)wdw * NH + h) << 12) + g * 4) = pk;
            }
        }
    }
}

// R5/R9: Q/K/V all live in REGISTERS — no Q/K LDS round-trip.
// Phase 1 computes Qt/Kt via SWAPPED operands: mfma(W_rowfrag, X_frag) gives
// D[d][t] (d in qq*4+r, t in cc) == the K=16 A/B frag layout for S directly.
// V stays unswapped (vq = A-frag of O^T = V^T P^T). Only P round-trips LDS
// (softmax-row vs contraction-dim transpose is inherent).
// LDS pool (32768 B). Per-wave region = P [64 rows][64] bf16 3-bit-swizzled
// = 8192 B. Block-shared phase-disjoint overlays:
//   X @0 [64][136] bf16 = 17408 (dead after barrier 2)
//   O @0 [64][136] bf16 = 17408 (after barrier 3)
// R9 spill fix: launch_bounds(256,3) -> 170-reg budget (R5's (256,4) forced
// 128 against ~145 live -> 57 MB of scratch). Bias loads moved inside phase 1
// sections to shorten lifetimes. NOTE: launch_bounds is a cap, not a floor —
// if alloc lands <=128 the HW still runs 4 blocks/CU.
#define RWAVE 8192
#define OSTR  136
#define LDSB  32768

__global__ __launch_bounds__(256, 3) void wmsa_main(
    const float* __restrict__ x,
    const float* __restrict__ qkvb, const float* __restrict__ projb,
    const short* __restrict__ wqkv, const short* __restrict__ wproj,
    const short* __restrict__ cmb, float* __restrict__ out)
{
    __shared__ __align__(16) char pool[LDSB];
    short* lds = (short*)pool;

    const int b    = blockIdx.x;
    const int wdw  = b & 63;
    const int tid  = threadIdx.x;
    const int wave = tid >> 6;
    const int lane = tid & 63;
    const int qq   = lane >> 4;        // quad 0..3
    const int cc   = lane & 15;
    const int ccl  = cc & 7, cch = cc >> 3, cm3 = cc & 3;

    const int colbase = wave * 32 + cc;

    // ---------------- Phase 0: stage x -> bf16 LDS (stride 136), zero pad rows ----------------
    {
        const float* xb = x + (size_t)b * NT * DIM;
        for (int i = tid; i < NT * 32; i += 256) {
            int t = i >> 5, c4 = (i & 31) << 2;
            float4 v = *(const float4*)(xb + t * DIM + c4);
            *(ulla*)(lds + t * 136 + c4) = pk4(v.x, v.y, v.z, v.w);
        }
        for (int i = tid; i < (64 - NT) * 32; i += 256) {   // zero rows 49..63
            int t = NT + (i >> 5), c4 = (i & 31) << 2;
            *(ulla*)(lds + t * 136 + c4) = 0ull;
        }
    }
    __syncthreads();   // B1: X staged

    // A-frags of X for all 4 row tiles (held in regs through phase 1)
    short8 af[4][4];
    #pragma unroll
    for (int it = 0; it < 4; ++it)
        #pragma unroll
        for (int ks = 0; ks < 4; ++ks)
            af[it][ks] = *(const short8a*)(lds + (it * 16 + cc) * 136 + ks * 32 + qq * 8);
    __syncthreads();   // B2: X reads done; per-wave P regions may be written

    short* pw = (short*)(pool + wave * RWAVE);   // P [64][64] bf16, 3-bit swizzle

    // Q/K transposed frags (K=16 layout) + V frags, all in registers.
    short4v qt[2][4], kt[2][4], vq[2][4];

    // ---------------- Phase 1: wave h computes Qt/Kt/V of head h (all -> regs) ----------------
    #pragma unroll
    for (int jt6 = 0; jt6 < 6; ++jt6) {
        const int sec = jt6 >> 1, hlf = jt6 & 1;             // compile-time
        short8 bfc[4];
        {
            const int cn = sec * DIM + colbase + hlf * 16;   // W row (=outdim) per lane cc
            #pragma unroll
            for (int ks = 0; ks < 4; ++ks)
                bfc[ks] = *(const short8a*)(wqkv + cn * DIM + ks * 32 + qq * 8);
        }
        if (sec < 2) {
            // SWAPPED: D[d][t] = sum_c W[d][c] X[t][c]; A=W-rows, B=X.
            // Bias per OUTPUT DIM (d = qq*4+r); loaded here (L1-hot) to keep
            // its register lifetime inside the section. Q bias pre-scaled.
            float4 b4 = *(const float4*)(qkvb + sec * DIM + wave * 32 + hlf * 16 + qq * 4);
            if (sec == 0) { b4.x *= SCALEQ; b4.y *= SCALEQ; b4.z *= SCALEQ; b4.w *= SCALEQ; }
            const floatx4 cinit = {b4.x, b4.y, b4.z, b4.w};
            #pragma unroll
            for (int tt = 0; tt < 4; ++tt) {
                floatx4 acc = cinit;
                #pragma unroll
                for (int ks = 0; ks < 4; ++ks)
                    acc = __builtin_amdgcn_mfma_f32_16x16x32_bf16(bfc[ks], af[tt][ks], acc, 0, 0, 0);
                if (sec == 0) qt[hlf][tt] = pack4(acc); else kt[hlf][tt] = pack4(acc);
            }
        } else {
            // V unswapped: D[t][d]; lane holds d=hlf*16+cc, tokens in regs —
            // exactly the A-frag of O^T = V^T P^T.
            float bvv = qkvb[2 * DIM + colbase + hlf * 16];
            const floatx4 cinit = {bvv, bvv, bvv, bvv};
            #pragma unroll
            for (int it = 0; it < 4; ++it) {
                floatx4 acc = cinit;
                #pragma unroll
                for (int ks = 0; ks < 4; ++ks)
                    acc = __builtin_amdgcn_mfma_f32_16x16x32_bf16(af[it][ks], bfc[ks], acc, 0, 0, 0);
                vq[hlf][it] = pack4(acc);
            }
        }
    }

    // prefetch all 16 S-tile C-inits (bias+mask combined, bf16 frag layout)
    short4v cm[16];
    {
        const short* cw = cmb + (((size_t)wdw * NH + wave) << 12);
        #pragma unroll
        for (int t16 = 0; t16 < 16; ++t16)
            cm[t16] = *(const short4a*)(cw + t16 * 256 + qq * 64 + cc * 4);
    }

    // ---------------- Phase 2: S = Q K^T from regs (K=16), exp, store RAW P ----------------
    // S[t][m]: t = qq*4+r, m = cc — same lane mapping as before, so cmb and
    // the P store/swizzle are unchanged. P stored UNNORMALIZED (rowsum via
    // ones-MFMA in phase 3).
    #pragma unroll
    for (int it = 0; it < 4; ++it) {
        floatx4 s[4];
        #pragma unroll
        for (int jt = 0; jt < 4; ++jt) {
            short4v cb = cm[it * 4 + jt];
            floatx4 ci = {b2f(cb.x), b2f(cb.y), b2f(cb.z), b2f(cb.w)};
            ci = MFMA16(qt[0][it], kt[0][jt], ci);
            s[jt] = MFMA16(qt[1][it], kt[1][jt], ci);
        }
        #pragma unroll
        for (int r = 0; r < 4; ++r) {
            int t = it * 16 + qq * 4 + r;
            #pragma unroll
            for (int jt = 0; jt < 4; ++jt) {
                float ee = __expf(s[jt][r]);   // pads -> exp(-1e30)=0
                int g = (jt * 2 + cch) ^ r ^ ((qq & 1) << 2);
                pw[t * 64 + (g << 3) + ccl] = f2b(ee);
            }
        }
    }
    __asm__ volatile("" ::: "memory");   // intra-wave phase fence: P stores -> PV loads

    // ---------------- Phase 3: O^T = V^T P^T and rowsum = 1^T P^T (K=16) ----------------
    // o[hlf][tt]: lane holds O^T[d=hlf*16+qq*4+r][t=tt*16+cc].
    floatx4 o[2][4];
    const short BONE = (short)0x3F80;    // bf16 1.0
    const short4v ones4 = {BONE, BONE, BONE, BONE};
    #pragma unroll
    for (int tt = 0; tt < 4; ++tt) {
        short4v ptb[4];
        #pragma unroll
        for (int kt4 = 0; kt4 < 4; ++kt4) {
            int g = (kt4 * 2 + (qq >> 1)) ^ cm3 ^ (((cc >> 2) & 1) << 2);
            ptb[kt4] = *(const short4a*)(pw + (tt * 16 + cc) * 64 + (g << 3) + (qq & 1) * 4);
        }
        floatx4 a0 = {0.f, 0.f, 0.f, 0.f}, a1 = a0, sm = a0;
        #pragma unroll
        for (int kt4 = 0; kt4 < 4; ++kt4) {
            a0 = MFMA16(vq[0][kt4], ptb[kt4], a0);
            a1 = MFMA16(vq[1][kt4], ptb[kt4], a1);
            sm = MFMA16(ones4, ptb[kt4], sm);
        }
        float inv = 1.0f / sm[0];        // all 4 rows of sm are identical
        #pragma unroll
        for (int r = 0; r < 4; ++r) { a0[r] *= inv; a1[r] *= inv; }
        o[0][tt] = a0; o[1][tt] = a1;
    }

    // prefetch proj B-frags jt=0,1 + all 8 proj biases (issued before the barriers,
    // cannot be sunk past them -> latency overlaps O round-trip)
    short8 pcur[4], pnxt[4];
    float pbv[8];
    #pragma unroll
    for (int ks = 0; ks < 4; ++ks) {
        pcur[ks] = *(const short8a*)(wproj + cc * DIM + ks * 32 + qq * 8);
        pnxt[ks] = *(const short8a*)(wproj + (16 + cc) * DIM + ks * 32 + qq * 8);
    }
    #pragma unroll
    for (int j = 0; j < 8; ++j) pbv[j] = projb[j * 16 + cc];

    __syncthreads();   // B3: all P reads done -> O may overlay per-wave P regions

    // O store: O^T regs pack 4 consecutive features per b64 (8 writes)
    short* ow = (short*)pool;   // O [64 tokens][OSTR=136], features 0..127
    #pragma unroll
    for (int hlf = 0; hlf < 2; ++hlf)
        #pragma unroll
        for (int tt = 0; tt < 4; ++tt) {
            int t  = tt * 16 + cc;
            int f0 = wave * 32 + hlf * 16 + qq * 4;
            *(ulla*)(ow + t * OSTR + f0) =
                pk4(o[hlf][tt][0], o[hlf][tt][1], o[hlf][tt][2], o[hlf][tt][3]);
        }
    __syncthreads();   // B4: O visible

    // ---------------- Phase 4: proj GEMM (depth-2 pipelined B-frags) ----------------
    {
        short8 a2[4];
        #pragma unroll
        for (int ks = 0; ks < 4; ++ks)
            a2[ks] = *(const short8a*)(ow + (wave * 16 + cc) * OSTR + ks * 32 + qq * 8);
        float* outb = out + (size_t)b * NT * DIM;
        #pragma unroll
        for (int jt = 0; jt < 8; ++jt) {
            short8 pfut[4];
            if (jt < 6) {
                int cn = (jt + 2) * 16 + cc;
                #pragma unroll
                for (int ks = 0; ks < 4; ++ks)
                    pfut[ks] = *(const short8a*)(wproj + cn * DIM + ks * 32 + qq * 8);
            }
            float pb = pbv[jt];
            floatx4 acc = {pb, pb, pb, pb};
            #pragma unroll
            for (int ks = 0; ks < 4; ++ks)
                acc = __builtin_amdgcn_mfma_f32_16x16x32_bf16(a2[ks], pcur[ks], acc, 0, 0, 0);
            int col = jt * 16 + cc;
            #pragma unroll
            for (int r = 0; r < 4; ++r) {
                int row = wave * 16 + qq * 4 + r;
                if (row < NT) outb[row * DIM + col] = acc[r];
            }
            #pragma unroll
            for (int ks = 0; ks < 4; ++ks) { pcur[ks] = pnxt[ks]; pnxt[ks] = pfut[ks]; }
        }
    }
}

extern "C" void kernel_launch(void* const* d_in, const int* in_sizes, int n_in,
                              void* d_out, int out_size, void* d_ws, size_t ws_size,
                              hipStream_t stream) {
    const float* x     = (const float*)d_in[0];   // (4096,49,128)
    const float* mask  = (const float*)d_in[1];   // (64,49,49)
    const float* qkvw  = (const float*)d_in[2];   // (384,128)
    const float* qkvb  = (const float*)d_in[3];   // (384)
    const float* projw = (const float*)d_in[4];   // (128,128)
    const float* projb = (const float*)d_in[5];   // (128)
    const float* btab  = (const float*)d_in[6];   // (169,4)
    const int*   ridx  = (const int*)d_in[7];     // (49,49)
    float* outp = (float*)d_out;

    short* wqkv  = (short*)d_ws;                      //   98304 B
    short* wproj = (short*)((char*)d_ws + 98304);     //   32768 B
    short* cmb   = (short*)((char*)d_ws + 131072);    // 2097152 B (total 2.23 MB)

    wmsa_prep<<<64, 256, 0, stream>>>(qkvw, projw, btab, ridx, mask, wqkv, wproj, cmb);
    wmsa_main<<<4096, 256, 0, stream>>>(x, qkvb, projb, wqkv, wproj, cmb, outp);
}

// Round 10
// 295.141 us; speedup vs baseline: 1.0450x; 1.0450x over previous
//
#include <hip/hip_runtime.h>

#define NT   49      // tokens per window
#define HD   32      // head dim
#define NH   4
#define DIM  128
#define SCALEQ 0.17677669529663687f  // 32^-0.5

typedef __attribute__((ext_vector_type(8))) short short8;
typedef __attribute__((ext_vector_type(4))) short short4v;
typedef __attribute__((ext_vector_type(4))) float floatx4;
// may_alias versions: all LDS/global type-punned accesses go through these so
// TBAA cannot reorder stores/loads across the barrier-free phase chain.
typedef short8 short8a __attribute__((may_alias));
typedef short4v short4a __attribute__((may_alias));
typedef unsigned long long ulla __attribute__((may_alias));
typedef unsigned long long ull;

// Conversions: hand-rolled RNE fp32->bf16 (bit-exact across all passing runs).
// Quarantined: <hip/hip_bf16.h> (R6/R7 container deaths) and inline-asm
// v_cvt_pk_bf16_f32 (R8 NaN). Do not reintroduce without isolated A/B.
__device__ __forceinline__ short f2b(float f) {
    union { float f; unsigned u; } v; v.f = f;
    return (short)((v.u + 0x7fffu + ((v.u >> 16) & 1u)) >> 16);  // RNE fp32->bf16
}
__device__ __forceinline__ ull pk4(float a, float b, float c, float d) {
    return  (ull)(unsigned short)f2b(a)
         | ((ull)(unsigned short)f2b(b) << 16)
         | ((ull)(unsigned short)f2b(c) << 32)
         | ((ull)(unsigned short)f2b(d) << 48);
}
__device__ __forceinline__ short4v pack4(floatx4 a) {
    short4v r;
    r[0] = f2b(a[0]); r[1] = f2b(a[1]); r[2] = f2b(a[2]); r[3] = f2b(a[3]);
    return r;
}
__device__ __forceinline__ float b2f(short s) {
    union { unsigned u; float f; } v; v.u = ((unsigned)(unsigned short)s) << 16;
    return v.f;
}

// K=16 MFMA (A[row=cc][k=qq*4+e], B[col=cc][k=qq*4+e]) — HW-validated R3-R9.
// Fallback: zero-padded K=32 (elements at e=0..3 map to k32=qq*8+e identically
// for A and B, so the contraction equals the K=16 product).
#if __has_builtin(__builtin_amdgcn_mfma_f32_16x16x16bf16_1k)
__device__ __forceinline__ floatx4 MFMA16(short4v a, short4v b, floatx4 c) {
    return __builtin_amdgcn_mfma_f32_16x16x16bf16_1k(a, b, c, 0, 0, 0);
}
#else
__device__ __forceinline__ floatx4 MFMA16(short4v a, short4v b, floatx4 c) {
    short8 a8 = {a[0], a[1], a[2], a[3], 0, 0, 0, 0};
    short8 b8 = {b[0], b[1], b[2], b[3], 0, 0, 0, 0};
    return __builtin_amdgcn_mfma_f32_16x16x32_bf16(a8, b8, c, 0, 0, 0);
}
#endif

// ---------- prologue ----------
// 64 blocks (one per window). Stage ridx/btab/mask in LDS, emit the combined
// bias+mask table (cmb) in MFMA frag layout + convert weights to bf16.
// cmb[wdw][h][(it*4+jt)*256 + qq*64 + cc*4 + r] bf16 = bias[h] + mask[wdw];
// col>=49 -> -1e30 (masks key pads via C-init), row>=49 -> 0. wqkv Q-section
// pre-scaled by hd^-0.5.
__global__ __launch_bounds__(256) void wmsa_prep(
        const float* __restrict__ qkvw, const float* __restrict__ projw,
        const float* __restrict__ btab, const int* __restrict__ ridx,
        const float* __restrict__ mask,
        short* __restrict__ wqkv, short* __restrict__ wproj,
        short* __restrict__ cmb) {
    __shared__ __align__(16) int   s_ridx[NT * NT];        // 9604 B
    __shared__ __align__(16) float s_btab[169 * 4];        // 2704 B (float4 rows)
    __shared__ __align__(16) float s_mask[NT * NT];        // 9604 B

    const int wdw = blockIdx.x;
    const int tid = threadIdx.x;

    // ---- weight conversion: one float4 group per thread (grid covers all) ----
    {
        int g = wdw * 256 + tid;          // 0..16383; 3*128*128/4 = 12288 qkv groups
        const float* src = (g < 12288) ? (qkvw + g * 4) : (projw + (g - 12288) * 4);
        float4 v = *(const float4*)src;
        float s = (g < 4096) ? SCALEQ : 1.0f;   // first DIM*DIM elements = Q rows
        ull pk = pk4(v.x * s, v.y * s, v.z * s, v.w * s);
        if (g < 12288) *(ulla*)(wqkv + g * 4) = pk;
        else           *(ulla*)(wproj + (g - 12288) * 4) = pk;
    }

    // ---- stage gather tables (coalesced) ----
    for (int i = tid; i < NT * NT; i += 256) s_ridx[i] = ridx[i];
    for (int i = tid; i < 169 * 4; i += 256) s_btab[i] = btab[i];
    {
        const float* mw = mask + (size_t)wdw * NT * NT;
        for (int i = tid; i < NT * NT; i += 256) s_mask[i] = mw[i];
    }
    __syncthreads();

    // ---- emit combined table for this window: 4 heads x 4096 bf16 ----
    // group g encodes (it,jt,qq,cc); the 4 consecutive shorts are r=0..3.
    #pragma unroll
    for (int gi = 0; gi < 4; ++gi) {
        int g = gi * 256 + tid;                       // 0..1023
        int cc = g & 15, qq = (g >> 4) & 3, tile = g >> 6;
        int it = tile >> 2, jt = tile & 3;
        int col = jt * 16 + cc;
        int rowb = it * 16 + qq * 4;
        if (col >= NT) {
            ull m16 = (unsigned short)f2b(-1e30f);
            ull pk = m16 | (m16 << 16) | (m16 << 32) | (m16 << 48);
            #pragma unroll
            for (int h = 0; h < NH; ++h)
                *(ulla*)(cmb + (((size_t)wdw * NH + h) << 12) + g * 4) = pk;
        } else {
            float bt[4][4], mv[4];
            #pragma unroll
            for (int r = 0; r < 4; ++r) {
                int row = rowb + r;
                if (row >= NT) {
                    bt[r][0] = bt[r][1] = bt[r][2] = bt[r][3] = 0.f;
                    mv[r] = 0.f;
                } else {
                    int ri = s_ridx[row * NT + col];
                    float4 b4 = *(const float4*)(s_btab + ri * 4);  // all 4 heads
                    bt[r][0] = b4.x; bt[r][1] = b4.y; bt[r][2] = b4.z; bt[r][3] = b4.w;
                    mv[r] = s_mask[row * NT + col];
                }
            }
            #pragma unroll
            for (int h = 0; h < NH; ++h) {
                ull pk = pk4(bt[0][h] + mv[0], bt[1][h] + mv[1],
                             bt[2][h] + mv[2], bt[3][h] + mv[3]);
                *(ulla*)(cmb + (((size_t)wdw * NH + h) << 12) + g * 4) = pk;
            }
        }
    }
}

// R10 = R4 structure (best verified: 155 us, VGPR 60, no spill) + R9's
// independently-verified transposed PV epilogue.
// LDS pool (32768 B). Per-wave region R=8192 B:
//   Q @+0    [64 rows][32] bf16, XOR-swizzled 8-short groups   = 4096
//   K @+4096 same                                              = 4096
//   P @+0    [64 rows][64] bf16 3-bit-swizzled (overlays Q+K)  = 8192
//   V lives in REGISTERS (vq = A-frag of O^T = V^T P^T, K=16 MFMAs).
// Block-shared, phase-disjoint overlays:
//   X @0 [64][136] bf16 = 17408 (dead after barrier 2)
//   O @0 [64][136] bf16 = 17408 (after barrier 3)
// Phase 3 computes O^T (R9 graft): lane holds 4 consecutive FEATURES ->
// packed b64 O-stores (8 vs 32 scalar), 4 reciprocals (vs 16).
// launch_bounds(256,4): 128-reg budget — R4 measured VGPR 60, zero spill.
// Perf ledger: R3 (256,5)=393us spill; R5/R9 reg-resident QK=166-176us
// (occupancy loss + residual spill); R4=155us. Spill signature: WRITE>>100MB.
#define RWAVE 8192
#define OSTR  136
#define LDSB  32768

__global__ __launch_bounds__(256, 4) void wmsa_main(
    const float* __restrict__ x,
    const float* __restrict__ qkvb, const float* __restrict__ projb,
    const short* __restrict__ wqkv, const short* __restrict__ wproj,
    const short* __restrict__ cmb, float* __restrict__ out)
{
    __shared__ __align__(16) char pool[LDSB];
    short* lds = (short*)pool;

    const int b    = blockIdx.x;
    const int wdw  = b & 63;
    const int tid  = threadIdx.x;
    const int wave = tid >> 6;
    const int lane = tid & 63;
    const int qq   = lane >> 4;        // quad 0..3
    const int cc   = lane & 15;
    const int ccl  = cc & 7, cch = cc >> 3, cm3 = cc & 3;

    // ---- prefetch all 6 qkv biases (complete during staging) ----
    const int colbase = wave * 32 + cc;
    float biasv[6];
    #pragma unroll
    for (int j = 0; j < 6; ++j)
        biasv[j] = qkvb[(j >> 1) * DIM + colbase + (j & 1) * 16];

    // ---------------- Phase 0: stage x -> bf16 LDS (stride 136), zero pad rows ----------------
    {
        const float* xb = x + (size_t)b * NT * DIM;
        for (int i = tid; i < NT * 32; i += 256) {
            int t = i >> 5, c4 = (i & 31) << 2;
            float4 v = *(const float4*)(xb + t * DIM + c4);
            *(ulla*)(lds + t * 136 + c4) = pk4(v.x, v.y, v.z, v.w);
        }
        for (int i = tid; i < (64 - NT) * 32; i += 256) {   // zero rows 49..63
            int t = NT + (i >> 5), c4 = (i & 31) << 2;
            *(ulla*)(lds + t * 136 + c4) = 0ull;
        }
    }
    __syncthreads();   // B1: X staged

    // A-frags of X for all 4 row tiles (held in regs through phase 1)
    short8 af[4][4];
    #pragma unroll
    for (int it = 0; it < 4; ++it)
        #pragma unroll
        for (int ks = 0; ks < 4; ++ks)
            af[it][ks] = *(const short8a*)(lds + (it * 16 + cc) * 136 + ks * 32 + qq * 8);
    __syncthreads();   // B2: X reads done; per-wave regions may be written

    short* qw = (short*)(pool + wave * RWAVE);
    short* kw = qw + 2048;     // +4096 B
    short* pw = qw;            // P overlays Q+K after S

    // V in registers: vq[hlf][it] = 4 consecutive tokens (bf16) for dim
    // hlf*16+cc == the A-frag of O^T = V^T P^T. Static indices only.
    short4v vq[2][4];

    // ---------------- Phase 1: wave h computes Q/K/V of head h ----------------
    #pragma unroll
    for (int jt6 = 0; jt6 < 6; ++jt6) {
        const int sec = jt6 >> 1, hlf = jt6 & 1;             // compile-time
        short8 bfc[4];
        {
            const int cn = sec * DIM + colbase + hlf * 16;
            #pragma unroll
            for (int ks = 0; ks < 4; ++ks)
                bfc[ks] = *(const short8a*)(wqkv + cn * DIM + ks * 32 + qq * 8);
        }
        float bias = biasv[jt6];
        if (sec == 0) bias *= SCALEQ;
        const floatx4 cinit = {bias, bias, bias, bias};
        #pragma unroll
        for (int it = 0; it < 4; ++it) {
            floatx4 acc = cinit;
            #pragma unroll
            for (int ks = 0; ks < 4; ++ks)
                acc = __builtin_amdgcn_mfma_f32_16x16x32_bf16(af[it][ks], bfc[ks], acc, 0, 0, 0);
            if (sec == 2) {                                   // V: stays in registers
                vq[hlf][it] = pack4(acc);
            } else {                                          // Q/K: [t][d] swizzled
                short* dst = (sec == 0) ? qw : kw;
                int gb = hlf * 2 + cch;                       // d>>3
                #pragma unroll
                for (int r = 0; r < 4; ++r) {                 // t&3 == r
                    int t = it * 16 + qq * 4 + r;
                    dst[t * 32 + ((gb ^ r) << 3) + ccl] = f2b(acc[r]);
                }
            }
        }
    }

    // prefetch all 16 S-tile C-inits (bias+mask combined, bf16 frag layout);
    // placed after phase 1 to keep phase-1 VGPR pressure under the budget.
    short4v cm[16];
    {
        const short* cw = cmb + (((size_t)wdw * NH + wave) << 12);
        #pragma unroll
        for (int t16 = 0; t16 < 16; ++t16)
            cm[t16] = *(const short4a*)(cw + t16 * 256 + qq * 64 + cc * 4);
    }
    __asm__ volatile("" ::: "memory");   // intra-wave phase fence: QKV stores -> S loads

    // ---------------- Phase 2: S = Q K^T (+combined C-init), exp, store RAW P ----------------
    // P stored UNNORMALIZED; denominators come from rowsum = 1^T P^T MFMAs in
    // phase 3; O scaled by 1/rowsum after PV. P swizzle is 3-bit:
    // g = (col>>3) ^ (t&3) ^ (((t>>2)&1)<<2).
    {
        short8 qf[4], kf[4];
        #pragma unroll
        for (int t = 0; t < 4; ++t) {
            qf[t] = *(const short8a*)(qw + (t * 16 + cc) * 32 + ((qq ^ cm3) << 3));
            kf[t] = *(const short8a*)(kw + (t * 16 + cc) * 32 + ((qq ^ cm3) << 3));
        }
        #pragma unroll
        for (int it = 0; it < 4; ++it) {
            floatx4 s[4];
            #pragma unroll
            for (int jt = 0; jt < 4; ++jt) {
                short4v cb = cm[it * 4 + jt];
                floatx4 ci = {b2f(cb.x), b2f(cb.y), b2f(cb.z), b2f(cb.w)};
                s[jt] = __builtin_amdgcn_mfma_f32_16x16x32_bf16(qf[it], kf[jt], ci, 0, 0, 0);
            }
            #pragma unroll
            for (int r = 0; r < 4; ++r) {
                int t = it * 16 + qq * 4 + r;
                #pragma unroll
                for (int jt = 0; jt < 4; ++jt) {
                    float ee = __expf(s[jt][r]);   // pads -> exp(-1e30)=0
                    int g = (jt * 2 + cch) ^ r ^ ((qq & 1) << 2);
                    pw[t * 64 + (g << 3) + ccl] = f2b(ee);
                }
            }
        }
    }
    __asm__ volatile("" ::: "memory");   // intra-wave phase fence: P stores -> PV loads

    // ---------------- Phase 3 (R9 graft): O^T = V^T P^T, rowsum = 1^T P^T ----------------
    // o[hlf][tt]: lane holds O^T[d=hlf*16+qq*4+r][t=tt*16+cc]. Verified
    // bit-correct in R9 against the identical phase-2 P layout.
    floatx4 o[2][4];
    const short BONE = (short)0x3F80;    // bf16 1.0
    const short4v ones4 = {BONE, BONE, BONE, BONE};
    #pragma unroll
    for (int tt = 0; tt < 4; ++tt) {
        short4v ptb[4];
        #pragma unroll
        for (int kt4 = 0; kt4 < 4; ++kt4) {
            int g = (kt4 * 2 + (qq >> 1)) ^ cm3 ^ (((cc >> 2) & 1) << 2);
            ptb[kt4] = *(const short4a*)(pw + (tt * 16 + cc) * 64 + (g << 3) + (qq & 1) * 4);
        }
        floatx4 a0 = {0.f, 0.f, 0.f, 0.f}, a1 = a0, sm = a0;
        #pragma unroll
        for (int kt4 = 0; kt4 < 4; ++kt4) {
            a0 = MFMA16(vq[0][kt4], ptb[kt4], a0);
            a1 = MFMA16(vq[1][kt4], ptb[kt4], a1);
            sm = MFMA16(ones4, ptb[kt4], sm);
        }
        float inv = 1.0f / sm[0];        // all 4 rows of sm are identical
        #pragma unroll
        for (int r = 0; r < 4; ++r) { a0[r] *= inv; a1[r] *= inv; }
        o[0][tt] = a0; o[1][tt] = a1;
    }

    // prefetch proj B-frags jt=0,1 + all 8 proj biases (issued before the barriers,
    // cannot be sunk past them -> latency overlaps O round-trip)
    short8 pcur[4], pnxt[4];
    float pbv[8];
    #pragma unroll
    for (int ks = 0; ks < 4; ++ks) {
        pcur[ks] = *(const short8a*)(wproj + cc * DIM + ks * 32 + qq * 8);
        pnxt[ks] = *(const short8a*)(wproj + (16 + cc) * DIM + ks * 32 + qq * 8);
    }
    #pragma unroll
    for (int j = 0; j < 8; ++j) pbv[j] = projb[j * 16 + cc];

    __syncthreads();   // B3: all P reads done -> O may overlay per-wave regions

    // O store (R9 graft): O^T regs pack 4 consecutive features per b64
    // (8 writes, was 32 scalar ds_write_b16).
    short* ow = (short*)pool;   // O [64 tokens][OSTR=136], features 0..127
    #pragma unroll
    for (int hlf = 0; hlf < 2; ++hlf)
        #pragma unroll
        for (int tt = 0; tt < 4; ++tt) {
            int t  = tt * 16 + cc;
            int f0 = wave * 32 + hlf * 16 + qq * 4;
            *(ulla*)(ow + t * OSTR + f0) =
                pk4(o[hlf][tt][0], o[hlf][tt][1], o[hlf][tt][2], o[hlf][tt][3]);
        }
    __syncthreads();   // B4: O visible

    // ---------------- Phase 4: proj GEMM (depth-2 pipelined B-frags) ----------------
    {
        short8 a2[4];
        #pragma unroll
        for (int ks = 0; ks < 4; ++ks)
            a2[ks] = *(const short8a*)(ow + (wave * 16 + cc) * OSTR + ks * 32 + qq * 8);
        float* outb = out + (size_t)b * NT * DIM;
        #pragma unroll
        for (int jt = 0; jt < 8; ++jt) {
            short8 pfut[4];
            if (jt < 6) {
                int cn = (jt + 2) * 16 + cc;
                #pragma unroll
                for (int ks = 0; ks < 4; ++ks)
                    pfut[ks] = *(const short8a*)(wproj + cn * DIM + ks * 32 + qq * 8);
            }
            float pb = pbv[jt];
            floatx4 acc = {pb, pb, pb, pb};
            #pragma unroll
            for (int ks = 0; ks < 4; ++ks)
                acc = __builtin_amdgcn_mfma_f32_16x16x32_bf16(a2[ks], pcur[ks], acc, 0, 0, 0);
            int col = jt * 16 + cc;
            #pragma unroll
            for (int r = 0; r < 4; ++r) {
                int row = wave * 16 + qq * 4 + r;
                if (row < NT) outb[row * DIM + col] = acc[r];
            }
            #pragma unroll
            for (int ks = 0; ks < 4; ++ks) { pcur[ks] = pnxt[ks]; pnxt[ks] = pfut[ks]; }
        }
    }
}

extern "C" void kernel_launch(void* const* d_in, const int* in_sizes, int n_in,
                              void* d_out, int out_size, void* d_ws, size_t ws_size,
                              hipStream_t stream) {
    const float* x     = (const float*)d_in[0];   // (4096,49,128)
    const float* mask  = (const float*)d_in[1];   // (64,49,49)
    const float* qkvw  = (const float*)d_in[2];   // (384,128)
    const float* qkvb  = (const float*)d_in[3];   // (384)
    const float* projw = (const float*)d_in[4];   // (128,128)
    const float* projb = (const float*)d_in[5];   // (128)
    const float* btab  = (const float*)d_in[6];   // (169,4)
    const int*   ridx  = (const int*)d_in[7];     // (49,49)
    float* outp = (float*)d_out;

    short* wqkv  = (short*)d_ws;                      //   98304 B
    short* wproj = (short*)((char*)d_ws + 98304);     //   32768 B
    short* cmb   = (short*)((char*)d_ws + 131072);    // 2097152 B (total 2.23 MB)

    wmsa_prep<<<64, 256, 0, stream>>>(qkvw, projw, btab, ridx, mask, wqkv, wproj, cmb);
    wmsa_main<<<4096, 256, 0, stream>>>(x, qkvb, projb, wqkv, wproj, cmb, outp);
}